// Round 10
// baseline (62.345 us; speedup 1.0000x reference)
//
#include <hip/hip_runtime.h>
#include <math.h>

// Problem constants: B=32, L=2048, F=512, K=128, LOUT=1921
#define BB 32
#define LL 2048
#define FF 512
#define KK 128
#define LOUT (LL - KK + 1)      // 1921
#define TC 16                   // rows per chunk
#define NCH ((LOUT + TC - 1) / TC)   // 121 chunks per batch
#define F4 (FF / 4)             // 128
#define NXCD 8
#define JSTRIDE 16              // chunks per (b, xcd) stripe: 8*16=128 >= 121

// ---------------------------------------------------------------------------
// Kernel 1: tau[b,f] = sigmoid((x[b,L-1,:] . W[f,:] + bias[f]) / 10 - 3)
//           norm[b,f] = 1 / sum_{i=0..K-1} tau^i   (Horner)
//           tauK[b,f] = tau^K                       (7 squarings)
// ---------------------------------------------------------------------------
__global__ __launch_bounds__(128) void tau_kernel(const float* __restrict__ x,
                                                  const float* __restrict__ W,
                                                  const float* __restrict__ bias,
                                                  float* __restrict__ tau_out,
                                                  float* __restrict__ norm_out,
                                                  float* __restrict__ tauK_out) {
    __shared__ float feat[FF];
    const int b   = blockIdx.x >> 2;
    const int fq  = blockIdx.x & 3;
    const int tid = threadIdx.x;

    ((float4*)feat)[tid] =
        ((const float4*)(x + ((size_t)b * LL + (LL - 1)) * FF))[tid];
    __syncthreads();

    const int f = fq * 128 + tid;
    const float4* __restrict__ Wrow = (const float4*)(W + (size_t)f * FF);
    const float4* __restrict__ fv   = (const float4*)feat;

    float a0 = 0.f, a1 = 0.f, a2 = 0.f, a3 = 0.f;
#pragma unroll 4
    for (int j = 0; j < F4; j += 2) {
        float4 w0 = Wrow[j],     w1 = Wrow[j + 1];
        float4 x0 = fv[j],       x1 = fv[j + 1];
        a0 = fmaf(w0.x, x0.x, a0); a1 = fmaf(w0.y, x0.y, a1);
        a2 = fmaf(w0.z, x0.z, a2); a3 = fmaf(w0.w, x0.w, a3);
        a0 = fmaf(w1.x, x1.x, a0); a1 = fmaf(w1.y, x1.y, a1);
        a2 = fmaf(w1.z, x1.z, a2); a3 = fmaf(w1.w, x1.w, a3);
    }
    const float acc = (a0 + a1) + (a2 + a3);
    const float z   = (acc + bias[f]) * 0.1f - 3.0f;
    const float tau = 1.0f / (1.0f + expf(-z));

    float den = 1.0f;
#pragma unroll 8
    for (int i = 0; i < KK - 1; ++i) den = fmaf(den, tau, 1.0f);

    float tk = tau;
#pragma unroll
    for (int i = 0; i < 7; ++i) tk *= tk;

    const int idx = b * FF + f;
    tau_out[idx]  = tau;
    norm_out[idx] = 1.0f / den;
    tauK_out[idx] = tk;
}

// ---------------------------------------------------------------------------
// Kernel 2: XCD-chunked swizzle + low-amp truncation.
// Grid = 4096 blocks of 128 threads, decoded as bid = b*128 + j*8 + k:
//   k = bid & 7  -> XCD slot under round-robin dispatch,
//   c = k*JSTRIDE + j -> XCD k owns consecutive-c stripes per b,
//   consecutive bids on one XCD = consecutive c -> warm-up overlap rows
//   (chunks c and c+1 share T rows) are L2-hits instead of fabric/L3 trips.
// Tap cutoff 1e-5: T = ceil(-11.513/ln tau) ~ 4 for tau~0.05 (trunc error
// ~3e-5 << 0.104 threshold; clamps to full K as tau->1 => correct for any
// input). Read amp = (T+15)/16 ~ 1.19.
//   warm-up: S = fma(S, tau, x[t0+i]),  i in [K-T, K)
//   steady : S = fma(S, tau, x[t+K-1]); out[t] = norm*S   (15 iters)
// ---------------------------------------------------------------------------
__global__ __launch_bounds__(128) void fir_kernel(const float* __restrict__ x,
                                                  const float* __restrict__ tau_arr,
                                                  const float* __restrict__ norm_arr,
                                                  const float* __restrict__ tauK_arr,
                                                  float* __restrict__ out) {
    const int bid = blockIdx.x;
    const int k   = bid & 7;          // XCD slot (round-robin heuristic)
    const int t_  = bid >> 3;
    const int j   = t_ & 15;          // position within stripe
    const int b   = t_ >> 4;
    const int c   = k * JSTRIDE + j;
    if (c >= NCH) return;
    const int f4 = threadIdx.x;
    const int t0 = c * TC;
    const int nout = (t0 + TC <= LOUT) ? TC : (LOUT - t0);  // 16; last chunk 1

    const int idx4 = b * F4 + f4;
    const float4 tau = ((const float4*)tau_arr)[idx4];
    const float4 nrm = ((const float4*)norm_arr)[idx4];
    const float4 tk  = ((const float4*)tauK_arr)[idx4];

    const float4* __restrict__ xb = (const float4*)(x + (size_t)b * LL * FF) + f4;
    float4* __restrict__ ob = (float4*)(out + (size_t)b * LOUT * FF) + f4;

    // truncation length from 1e-5 tap cutoff (clamped to K for tau->1)
    const float tmax = fmaxf(fmaxf(tau.x, tau.y), fmaxf(tau.z, tau.w));
    int T = KK;
    if (tmax < 0.999f) {
        T = (int)ceilf(-11.512925f / logf(tmax));  // ln(1e-5)
        T = (T > KK) ? KK : (T < 2 ? 2 : T);
    }
    // wave-uniform T (extra taps only add accuracy; keeps lanes converged)
#pragma unroll
    for (int off = 32; off; off >>= 1) {
        const int o = __shfl_xor(T, off);
        T = (o > T) ? o : T;
    }

    // ---- warm-up: Horner over last T taps of window at t0 ----
    float4 S = make_float4(0.f, 0.f, 0.f, 0.f);
    for (int i = KK - T; i < KK; ++i) {
        const float4 v = xb[(size_t)(t0 + i) * F4];
        S.x = fmaf(S.x, tau.x, v.x);
        S.y = fmaf(S.y, tau.y, v.y);
        S.z = fmaf(S.z, tau.z, v.z);
        S.w = fmaf(S.w, tau.w, v.w);
    }
    ob[(size_t)t0 * F4] =
        make_float4(nrm.x * S.x, nrm.y * S.y, nrm.z * S.z, nrm.w * S.w);

    const bool fast =
        __all(tk.x == 0.f && tk.y == 0.f && tk.z == 0.f && tk.w == 0.f);

    if (fast) {
        if (nout == TC) {
#pragma unroll
            for (int kk = 1; kk < TC; ++kk) {
                const int t = t0 + kk;
                const float4 v = xb[(size_t)(t + KK - 1) * F4];
                S.x = fmaf(S.x, tau.x, v.x);
                S.y = fmaf(S.y, tau.y, v.y);
                S.z = fmaf(S.z, tau.z, v.z);
                S.w = fmaf(S.w, tau.w, v.w);
                ob[(size_t)t * F4] = make_float4(
                    nrm.x * S.x, nrm.y * S.y, nrm.z * S.z, nrm.w * S.w);
            }
        } else {
            for (int kk = 1; kk < nout; ++kk) {
                const int t = t0 + kk;
                const float4 v = xb[(size_t)(t + KK - 1) * F4];
                S.x = fmaf(S.x, tau.x, v.x);
                S.y = fmaf(S.y, tau.y, v.y);
                S.z = fmaf(S.z, tau.z, v.z);
                S.w = fmaf(S.w, tau.w, v.w);
                ob[(size_t)t * F4] = make_float4(
                    nrm.x * S.x, nrm.y * S.y, nrm.z * S.z, nrm.w * S.w);
            }
        }
    } else {
        // general sliding-window recurrence (correct for any tau)
        for (int kk = 1; kk < nout; ++kk) {
            const int t = t0 + kk;
            const float4 lead  = xb[(size_t)(t + KK - 1) * F4];
            const float4 trail = xb[(size_t)(t - 1) * F4];
            S.x = fmaf(S.x, tau.x, fmaf(-tk.x, trail.x, lead.x));
            S.y = fmaf(S.y, tau.y, fmaf(-tk.y, trail.y, lead.y));
            S.z = fmaf(S.z, tau.z, fmaf(-tk.z, trail.z, lead.z));
            S.w = fmaf(S.w, tau.w, fmaf(-tk.w, trail.w, lead.w));
            ob[(size_t)t * F4] = make_float4(
                nrm.x * S.x, nrm.y * S.y, nrm.z * S.z, nrm.w * S.w);
        }
    }
}

extern "C" void kernel_launch(void* const* d_in, const int* in_sizes, int n_in,
                              void* d_out, int out_size, void* d_ws, size_t ws_size,
                              hipStream_t stream) {
    const float* x    = (const float*)d_in[0];  // [B, L, F]
    const float* W    = (const float*)d_in[1];  // [F, F]
    const float* bias = (const float*)d_in[2];  // [F]
    float* out = (float*)d_out;                 // [B, LOUT, F]

    float* ws = (float*)d_ws;
    float* tau_arr  = ws;                 // [B*F]
    float* norm_arr = ws + BB * FF;       // [B*F]
    float* tauK_arr = ws + 2 * BB * FF;   // [B*F]

    tau_kernel<<<BB * 4, 128, 0, stream>>>(x, W, bias, tau_arr, norm_arr, tauK_arr);
    fir_kernel<<<BB * NXCD * JSTRIDE, 128, 0, stream>>>(x, tau_arr, norm_arr,
                                                        tauK_arr, out);
}

// Round 11
// 59.474 us; speedup vs baseline: 1.0483x; 1.0483x over previous
//
#include <hip/hip_runtime.h>
#include <math.h>

// Problem constants: B=32, L=2048, F=512, K=128, LOUT=1921
#define BB 32
#define LL 2048
#define FF 512
#define KK 128
#define LOUT (LL - KK + 1)      // 1921
#define TC 24                   // outputs per chunk
#define NCH ((LOUT + TC - 1) / TC)   // 81 chunks per batch
#define F4 (FF / 4)             // 128
#define T8 8                    // compile-time truncation (fast path iff T<=8)
#define NR (T8 + TC - 1)        // 31 rows loaded per thread, straight-line

// ---------------------------------------------------------------------------
// Kernel 1: tau[b,f] = sigmoid((x[b,L-1,:] . W[f,:] + bias[f]) / 10 - 3)
//           norm[b,f] = 1 / sum_{i=0..K-1} tau^i   (Horner)
//           tauK[b,f] = tau^K                       (7 squarings)
// ---------------------------------------------------------------------------
__global__ __launch_bounds__(128) void tau_kernel(const float* __restrict__ x,
                                                  const float* __restrict__ W,
                                                  const float* __restrict__ bias,
                                                  float* __restrict__ tau_out,
                                                  float* __restrict__ norm_out,
                                                  float* __restrict__ tauK_out) {
    __shared__ float feat[FF];
    const int b   = blockIdx.x >> 2;
    const int fq  = blockIdx.x & 3;
    const int tid = threadIdx.x;

    ((float4*)feat)[tid] =
        ((const float4*)(x + ((size_t)b * LL + (LL - 1)) * FF))[tid];
    __syncthreads();

    const int f = fq * 128 + tid;
    const float4* __restrict__ Wrow = (const float4*)(W + (size_t)f * FF);
    const float4* __restrict__ fv   = (const float4*)feat;

    float a0 = 0.f, a1 = 0.f, a2 = 0.f, a3 = 0.f;
#pragma unroll 4
    for (int j = 0; j < F4; j += 2) {
        float4 w0 = Wrow[j],     w1 = Wrow[j + 1];
        float4 x0 = fv[j],       x1 = fv[j + 1];
        a0 = fmaf(w0.x, x0.x, a0); a1 = fmaf(w0.y, x0.y, a1);
        a2 = fmaf(w0.z, x0.z, a2); a3 = fmaf(w0.w, x0.w, a3);
        a0 = fmaf(w1.x, x1.x, a0); a1 = fmaf(w1.y, x1.y, a1);
        a2 = fmaf(w1.z, x1.z, a2); a3 = fmaf(w1.w, x1.w, a3);
    }
    const float acc = (a0 + a1) + (a2 + a3);
    const float z   = (acc + bias[f]) * 0.1f - 3.0f;
    const float tau = 1.0f / (1.0f + expf(-z));

    float den = 1.0f;
#pragma unroll 8
    for (int i = 0; i < KK - 1; ++i) den = fmaf(den, tau, 1.0f);

    float tk = tau;
#pragma unroll
    for (int i = 0; i < 7; ++i) tk *= tk;

    const int idx = b * FF + f;
    tau_out[idx]  = tau;
    norm_out[idx] = 1.0f / den;
    tauK_out[idx] = tk;
}

// ---------------------------------------------------------------------------
// Kernel 2: one-shot load-batch version. Grid = B*NCH = 2592 blocks of 128
// threads; thread (b,c,f4) owns 24 output rows. FAST PATH (T<=8, tau^K~0):
// all NR=31 input rows are loaded in ONE straight-line batch of independent
// loads, fenced from the consumer chain by sched_barrier(0) -- all 31
// float4 are live across the fence, so the compiler CANNOT narrow the
// batch (the r5/r8 failure). 31 KB in flight per wave x ~10 waves/CU
// sustains the ~64KB/CU Little's-law requirement for ~6.3 TB/s.
// Fixed T8=8 taps: truncation error tau^8 (~2e-11 for this data's
// tau~0.05); computed-T > 8 (tau -> 1) takes the exact fallback path.
// Run-ahead rows clamped to the last row of x[b] (loaded, never stored).
// ---------------------------------------------------------------------------
__global__ __launch_bounds__(128) void fir_kernel(const float* __restrict__ x,
                                                  const float* __restrict__ tau_arr,
                                                  const float* __restrict__ norm_arr,
                                                  const float* __restrict__ tauK_arr,
                                                  float* __restrict__ out) {
    const int b  = blockIdx.x / NCH;
    const int c  = blockIdx.x % NCH;
    const int f4 = threadIdx.x;
    const int t0 = c * TC;
    const int nout = (t0 + TC <= LOUT) ? TC : (LOUT - t0);  // 24; tail 1

    const int idx4 = b * F4 + f4;
    const float4 tau = ((const float4*)tau_arr)[idx4];
    const float4 nrm = ((const float4*)norm_arr)[idx4];
    const float4 tk  = ((const float4*)tauK_arr)[idx4];

    const float4* __restrict__ xb = (const float4*)(x + (size_t)b * LL * FF) + f4;
    float4* __restrict__ ob = (float4*)(out + (size_t)b * LOUT * FF) + f4;

    // computed truncation length from 1e-5 tap cutoff (clamps to K as tau->1)
    const float tmax = fmaxf(fmaxf(tau.x, tau.y), fmaxf(tau.z, tau.w));
    int T = KK;
    if (tmax < 0.999f) {
        T = (int)ceilf(-11.512925f / logf(tmax));  // ln(1e-5)
        T = (T > KK) ? KK : (T < 2 ? 2 : T);
    }

    const bool fast = __all(
        T <= T8 && tk.x == 0.f && tk.y == 0.f && tk.z == 0.f && tk.w == 0.f);

    if (fast) {
        const int base_t = t0 + KK - T8;  // first of NR consecutive rows

        // ---- one-shot independent load batch (31 x 16B, all live) ----
        float4 v[NR];
#pragma unroll
        for (int j = 0; j < NR; ++j) {
            int t = base_t + j;
            t = (t < LL - 1) ? t : (LL - 1);  // clamp run-ahead (unused rows)
            v[j] = xb[(size_t)t * F4];
        }
        __builtin_amdgcn_sched_barrier(0);  // loads may not sink past here

        // ---- register-only Horner chain + progressive stores ----
        float4 S = make_float4(0.f, 0.f, 0.f, 0.f);
#pragma unroll
        for (int j = 0; j < NR; ++j) {
            S.x = fmaf(S.x, tau.x, v[j].x);
            S.y = fmaf(S.y, tau.y, v[j].y);
            S.z = fmaf(S.z, tau.z, v[j].z);
            S.w = fmaf(S.w, tau.w, v[j].w);
            const int k = j - (T8 - 1);   // output index within chunk
            if (k >= 0 && k < nout) {
                ob[(size_t)(t0 + k) * F4] = make_float4(
                    nrm.x * S.x, nrm.y * S.y, nrm.z * S.z, nrm.w * S.w);
            }
        }
    } else {
        // exact general path: full-K Horner warm-up + sliding window w/ tau^K
        float4 S = make_float4(0.f, 0.f, 0.f, 0.f);
        for (int i = 0; i < KK; ++i) {
            const float4 v = xb[(size_t)(t0 + i) * F4];
            S.x = fmaf(S.x, tau.x, v.x);
            S.y = fmaf(S.y, tau.y, v.y);
            S.z = fmaf(S.z, tau.z, v.z);
            S.w = fmaf(S.w, tau.w, v.w);
        }
        ob[(size_t)t0 * F4] = make_float4(nrm.x * S.x, nrm.y * S.y,
                                          nrm.z * S.z, nrm.w * S.w);
        for (int k = 1; k < nout; ++k) {
            const int t = t0 + k;
            const float4 lead  = xb[(size_t)(t + KK - 1) * F4];
            const float4 trail = xb[(size_t)(t - 1) * F4];
            S.x = fmaf(S.x, tau.x, fmaf(-tk.x, trail.x, lead.x));
            S.y = fmaf(S.y, tau.y, fmaf(-tk.y, trail.y, lead.y));
            S.z = fmaf(S.z, tau.z, fmaf(-tk.z, trail.z, lead.z));
            S.w = fmaf(S.w, tau.w, fmaf(-tk.w, trail.w, lead.w));
            ob[(size_t)t * F4] = make_float4(
                nrm.x * S.x, nrm.y * S.y, nrm.z * S.z, nrm.w * S.w);
        }
    }
}

extern "C" void kernel_launch(void* const* d_in, const int* in_sizes, int n_in,
                              void* d_out, int out_size, void* d_ws, size_t ws_size,
                              hipStream_t stream) {
    const float* x    = (const float*)d_in[0];  // [B, L, F]
    const float* W    = (const float*)d_in[1];  // [F, F]
    const float* bias = (const float*)d_in[2];  // [F]
    float* out = (float*)d_out;                 // [B, LOUT, F]

    float* ws = (float*)d_ws;
    float* tau_arr  = ws;                 // [B*F]
    float* norm_arr = ws + BB * FF;       // [B*F]
    float* tauK_arr = ws + 2 * BB * FF;   // [B*F]

    tau_kernel<<<BB * 4, 128, 0, stream>>>(x, W, bias, tau_arr, norm_arr, tauK_arr);
    fir_kernel<<<BB * NCH, 128, 0, stream>>>(x, tau_arr, norm_arr, tauK_arr, out);
}